// Round 2
// baseline (1233.055 us; speedup 1.0000x reference)
//
#include <hip/hip_runtime.h>
#include <hip/hip_bf16.h>
#include <stdint.h>
#include <math.h>

#define TT 1024
#define BB 512
#define FF 32
#define HH 64

typedef unsigned short u16;
typedef unsigned int u32;

__device__ __forceinline__ float bf2f(u16 u) {
    return __uint_as_float(((u32)u) << 16);
}
__device__ __forceinline__ u16 f2bf(float f) {
    u32 u = __float_as_uint(f);
    u32 r = (u + 0x7fffu + ((u >> 16) & 1u)) >> 16;
    return (u16)r;
}
__device__ __forceinline__ float sigm(float x) { return 1.f / (1.f + expf(-x)); }

// One block per sequence (512 blocks x 256 threads). Persistent weights in VGPRs.
// Encoder and decoder fused in a 1-step pipeline: iteration tt computes enc step tt
// and dec step tt-1. Thread roles:
//   Phase 1 (all 256): enc gate row t (32 x-FMA + 64 h-FMA) + half of dec gate row
//     rd=t&127 (48 FMA). p = t>>7 selects which half of the dec dot-product.
//   Phase 2: t<64 -> enc unit update; 64<=t<96 -> dec unit update + output store.
// Input dtype (fp32 vs packed bf16) detected on-device from x's bit patterns; the
// compute pipeline is fp32 regardless, only loads/stores branch.

__global__ __launch_bounds__(256, 2)
void lstm_ae_kernel(const void* __restrict__ x_,
                    const void* __restrict__ ewih_, const void* __restrict__ ewhh_,
                    const void* __restrict__ ebih_, const void* __restrict__ ebhh_,
                    const void* __restrict__ dwih_, const void* __restrict__ dwhh_,
                    const void* __restrict__ dbih_, const void* __restrict__ dbhh_,
                    void* __restrict__ out_)
{
    const int b = blockIdx.x;
    const int t = threadIdx.x;

    __shared__ __align__(16) float h_enc_s[HH];
    __shared__ __align__(16) float h_dec_s[FF];
    __shared__ __align__(16) float eg_s[256];
    __shared__ __align__(16) float dp_s[2][128];
    __shared__ __align__(16) float xbuf[2][64 * FF];

    // ---- dtype detection: bits[14:7] of each 32b word of x are a bf16 exponent
    // (narrow range) if packed-bf16, uniform-random mantissa bits if fp32. ----
    bool isbf;
    {
        const u32* xw = (const u32*)x_;
        int cnt = 0;
#pragma unroll
        for (int i = 0; i < 16; ++i) {
            u32 e = (xw[i] >> 7) & 0xffu;
            cnt += (e >= 0x70u && e <= 0x82u) ? 1 : 0;
        }
        isbf = (cnt >= 12);
    }

    // ---- zero-init LDS (cheap insurance), then load weights into registers ----
    eg_s[t] = 0.f;
    dp_s[t >> 7][t & 127] = 0.f;
    {
        float* z = &xbuf[0][0];
        for (int i = t; i < 2 * 64 * FF; i += 256) z[i] = 0.f;
    }
    if (t < HH) h_enc_s[t] = 0.f;
    if (t >= 64 && t < 96) h_dec_s[t - 64] = 0.f;

    float wih[32], whh[64], be;
    const int rd = t & 127;
    const int p  = t >> 7;
    float wd[48], bd;

    if (isbf) {
        const u16* ewih = (const u16*)ewih_;
        const u16* ewhh = (const u16*)ewhh_;
#pragma unroll
        for (int k = 0; k < 32; ++k) wih[k] = bf2f(ewih[t * 32 + k]);
#pragma unroll
        for (int k = 0; k < 64; ++k) whh[k] = bf2f(ewhh[t * 64 + k]);
        be = bf2f(((const u16*)ebih_)[t]) + bf2f(((const u16*)ebhh_)[t]);
        const u16* dwih = (const u16*)dwih_;
        const u16* dwhh = (const u16*)dwhh_;
        if (p == 0) {
#pragma unroll
            for (int k = 0; k < 48; ++k) wd[k] = bf2f(dwih[rd * 64 + k]);
            bd = bf2f(((const u16*)dbih_)[rd]) + bf2f(((const u16*)dbhh_)[rd]);
        } else {
#pragma unroll
            for (int k = 0; k < 16; ++k) wd[k] = bf2f(dwih[rd * 64 + 48 + k]);
#pragma unroll
            for (int k = 0; k < 32; ++k) wd[16 + k] = bf2f(dwhh[rd * 32 + k]);
            bd = 0.f;
        }
    } else {
        const float* ewih = (const float*)ewih_;
        const float* ewhh = (const float*)ewhh_;
#pragma unroll
        for (int k = 0; k < 32; ++k) wih[k] = ewih[t * 32 + k];
#pragma unroll
        for (int k = 0; k < 64; ++k) whh[k] = ewhh[t * 64 + k];
        be = ((const float*)ebih_)[t] + ((const float*)ebhh_)[t];
        const float* dwih = (const float*)dwih_;
        const float* dwhh = (const float*)dwhh_;
        if (p == 0) {
#pragma unroll
            for (int k = 0; k < 48; ++k) wd[k] = dwih[rd * 64 + k];
            bd = ((const float*)dbih_)[rd] + ((const float*)dbhh_)[rd];
        } else {
#pragma unroll
            for (int k = 0; k < 16; ++k) wd[k] = dwih[rd * 64 + 48 + k];
#pragma unroll
            for (int k = 0; k < 32; ++k) wd[16 + k] = dwhh[rd * 32 + k];
            bd = 0.f;
        }
    }

    // ---- x staging helper: chunk cn (64 steps = 2048 floats) -> xbuf[cn&1] ----
    const u16*   xs_bf = (const u16*)x_   + (size_t)b * TT * FF;
    const float* xs_f  = (const float*)x_ + (size_t)b * TT * FF;
    auto stage = [&](int cn) {
        float* dst = &xbuf[cn & 1][t * 8];
        if (isbf) {
            uint4 v = ((const uint4*)xs_bf)[cn * 256 + t];
            dst[0] = __uint_as_float(v.x << 16); dst[1] = __uint_as_float(v.x & 0xffff0000u);
            dst[2] = __uint_as_float(v.y << 16); dst[3] = __uint_as_float(v.y & 0xffff0000u);
            dst[4] = __uint_as_float(v.z << 16); dst[5] = __uint_as_float(v.z & 0xffff0000u);
            dst[6] = __uint_as_float(v.w << 16); dst[7] = __uint_as_float(v.w & 0xffff0000u);
        } else {
            const float4* s = (const float4*)xs_f + cn * 512 + 2 * t;
            float4 v0 = s[0], v1 = s[1];
            dst[0] = v0.x; dst[1] = v0.y; dst[2] = v0.z; dst[3] = v0.w;
            dst[4] = v1.x; dst[5] = v1.y; dst[6] = v1.z; dst[7] = v1.w;
        }
    };

    stage(0);
    float c_st = 0.f;   // c_enc for t<64, c_dec for 64<=t<96
    __syncthreads();

    u16*   out_bf = (u16*)out_;
    float* out_f  = (float*)out_;

    for (int tt = 0; tt <= TT; ++tt) {
        if ((tt & 63) == 0) {
            int cn = (tt >> 6) + 1;
            if (cn < 16) stage(cn);
        }

        // ---- Phase 1: gate mat-vecs ----
        float a0 = be, a1 = 0.f, a2 = 0.f, a3 = 0.f;
        {
            const float4* xr4 = (const float4*)(&xbuf[(tt >> 6) & 1][(tt & 63) << 5]);
#pragma unroll
            for (int k = 0; k < 8; ++k) {
                float4 v = xr4[k];
                a0 = fmaf(wih[4 * k + 0], v.x, a0);
                a1 = fmaf(wih[4 * k + 1], v.y, a1);
                a2 = fmaf(wih[4 * k + 2], v.z, a2);
                a3 = fmaf(wih[4 * k + 3], v.w, a3);
            }
        }
        float d0 = bd, d1 = 0.f, d2 = 0.f, d3 = 0.f;
        const float4* h4 = (const float4*)h_enc_s;
        if (p == 0) {
#pragma unroll
            for (int k = 0; k < 16; ++k) {
                float4 v = h4[k];
                a0 = fmaf(whh[4 * k + 0], v.x, a0);
                a1 = fmaf(whh[4 * k + 1], v.y, a1);
                a2 = fmaf(whh[4 * k + 2], v.z, a2);
                a3 = fmaf(whh[4 * k + 3], v.w, a3);
                if (k < 12) {
                    d0 = fmaf(wd[4 * k + 0], v.x, d0);
                    d1 = fmaf(wd[4 * k + 1], v.y, d1);
                    d2 = fmaf(wd[4 * k + 2], v.z, d2);
                    d3 = fmaf(wd[4 * k + 3], v.w, d3);
                }
            }
        } else {
#pragma unroll
            for (int k = 0; k < 16; ++k) {
                float4 v = h4[k];
                a0 = fmaf(whh[4 * k + 0], v.x, a0);
                a1 = fmaf(whh[4 * k + 1], v.y, a1);
                a2 = fmaf(whh[4 * k + 2], v.z, a2);
                a3 = fmaf(whh[4 * k + 3], v.w, a3);
                if (k >= 12) {
                    int j = k - 12;
                    d0 = fmaf(wd[4 * j + 0], v.x, d0);
                    d1 = fmaf(wd[4 * j + 1], v.y, d1);
                    d2 = fmaf(wd[4 * j + 2], v.z, d2);
                    d3 = fmaf(wd[4 * j + 3], v.w, d3);
                }
            }
            const float4* g4 = (const float4*)h_dec_s;
#pragma unroll
            for (int k = 0; k < 8; ++k) {
                float4 v = g4[k];
                d0 = fmaf(wd[16 + 4 * k + 0], v.x, d0);
                d1 = fmaf(wd[16 + 4 * k + 1], v.y, d1);
                d2 = fmaf(wd[16 + 4 * k + 2], v.z, d2);
                d3 = fmaf(wd[16 + 4 * k + 3], v.w, d3);
            }
        }
        eg_s[t] = (a0 + a1) + (a2 + a3);
        dp_s[p][rd] = (d0 + d1) + (d2 + d3);
        __syncthreads();

        // ---- Phase 2: nonlinear unit updates ----
        if (t < 64) {                 // encoder unit t, enc step tt
            if (tt < TT) {
                float ip = eg_s[t];
                float fp = eg_s[64 + t];
                float gp = eg_s[128 + t];
                float op = eg_s[192 + t];
                c_st = sigm(fp) * c_st + sigm(ip) * tanhf(gp);
                h_enc_s[t] = sigm(op) * tanhf(c_st);
            }
        } else if (t < 96) {          // decoder unit t-64, dec step tt-1
            if (tt >= 1) {
                int u = t - 64;
                float ip = dp_s[0][u]      + dp_s[1][u];
                float fp = dp_s[0][32 + u] + dp_s[1][32 + u];
                float gp = dp_s[0][64 + u] + dp_s[1][64 + u];
                float op = dp_s[0][96 + u] + dp_s[1][96 + u];
                c_st = sigm(fp) * c_st + sigm(ip) * tanhf(gp);
                float h = sigm(op) * tanhf(c_st);
                h_dec_s[u] = h;
                size_t idx = (size_t)b * TT * FF + (size_t)(tt - 1) * FF + u;
                if (isbf) out_bf[idx] = f2bf(h);
                else      out_f[idx]  = h;
            }
        }
        __syncthreads();
    }
}

extern "C" void kernel_launch(void* const* d_in, const int* in_sizes, int n_in,
                              void* d_out, int out_size, void* d_ws, size_t ws_size,
                              hipStream_t stream) {
    (void)in_sizes; (void)n_in; (void)out_size; (void)d_ws; (void)ws_size;
    lstm_ae_kernel<<<BB, 256, 0, stream>>>(d_in[0], d_in[1], d_in[2], d_in[3], d_in[4],
                                           d_in[5], d_in[6], d_in[7], d_in[8], d_out);
}

// Round 6
// 1145.138 us; speedup vs baseline: 1.0768x; 1.0768x over previous
//
#include <hip/hip_runtime.h>
#include <stdint.h>
#include <math.h>

#define TT 1024
#define FF 32
#define HH 64

typedef unsigned int u32;
typedef _Float16 f16;
typedef __attribute__((ext_vector_type(8))) _Float16 half8;  // 8 fp16 = 4 VGPRs (MFMA A/B frag)
typedef __attribute__((ext_vector_type(4))) float v4f;       // MFMA C/D frag

__device__ __forceinline__ float sigm(float x) { return 1.f / (1.f + expf(-x)); }

// load 8 consecutive fp32 -> fp16 octet (RNE), for A-fragment prep
__device__ __forceinline__ half8 ld8h(const float* p) {
    float4 a = *(const float4*)p, b = *(const float4*)(p + 4);
    half8 r;
    r[0] = (f16)a.x; r[1] = (f16)a.y; r[2] = (f16)a.z; r[3] = (f16)a.w;
    r[4] = (f16)b.x; r[5] = (f16)b.y; r[6] = (f16)b.z; r[7] = (f16)b.w;
    return r;
}

// ALL INPUTS/OUTPUT ARE FP32 (proven: round-2 WRITE_SIZE = 67.11 MB = fp32 out;
// round-2's runtime dtype detector chose the fp32 path and passed).
// One block per sequence (512 x 256 thr, 2 blocks/CU). Per step, one MFMA pass:
//   A (persistent VGPRs, fp32->fp16 converted once): 24 row-tiles of 16 rows x 96 K.
//     tiles 0..15  = encoder, K = [W_hh(64) | W_ih(32)], tile row m -> weight row
//                    (m&3)*64 + tile*4 + (m>>2)  (gate-interleaved)
//     tiles 16..23 = decoder, K = [V_ih(64) | V_hh(32)], weight row (m&3)*32 + ...
//   B (LDS Bst[16 cols][104 K-pad], fp16):
//     col 0 = [h_enc_hi | x_t]      col 1 = [h_enc_lo | 0]        (encoder)
//     col 2 = [h_enc_hi | h_dec_hi] col 3 = [h_enc_lo | h_dec_lo] (decoder)
//   D (col=lane&15, row=(lane>>4)*4+reg): lane (q,n) reg e = gate e of unit tile*4+q.
//   hi/lo column-pair partials stored to gpart via predicated ds_write_b128; phase 2
//   (96 threads) sums, applies nonlinearities in fp32, writes h back as fp16 hi+lo.
// Iteration tt computes enc step tt and dec step tt-1.

__global__ __launch_bounds__(256, 2)
void lstm_ae_mfma(const float* __restrict__ x,
                  const float* __restrict__ ewih, const float* __restrict__ ewhh,
                  const float* __restrict__ ebih, const float* __restrict__ ebhh,
                  const float* __restrict__ dwih, const float* __restrict__ dwhh,
                  const float* __restrict__ dbih, const float* __restrict__ dbhh,
                  float* __restrict__ out)
{
    const int b = blockIdx.x;
    const int t = threadIdx.x;
    const int w = t >> 6;        // wave 0..3
    const int l = t & 63;
    const int q = l >> 4;        // quad: A/B k-group, D row-group
    const int n = l & 15;        // A row-in-tile / B+D column

    __shared__ __align__(16) f16 Bst[16][104];       // B operand (col-major, +8 pad)
    __shared__ __align__(16) float xst[2][2048];     // x 64-step chunks, fp32, dbuf
    __shared__ __align__(16) float gpart[2][96 * 4]; // gate pre-act partials [hi/lo][unit*4+gate]

    // ---- persistent A fragments (fp32 -> fp16): lane holds A[m=n][k=q*8+j] ----
    half8 af[6][3];
#pragma unroll
    for (int i = 0; i < 6; ++i) {
        int tile = w * 6 + i;
        if (tile < 16) {
            int r = (n & 3) * 64 + tile * 4 + (n >> 2);          // enc W row
            af[i][0] = ld8h(ewhh + r * 64 + q * 8);
            af[i][1] = ld8h(ewhh + r * 64 + 32 + q * 8);
            af[i][2] = ld8h(ewih + r * 32 + q * 8);
        } else {
            int r = (n & 3) * 32 + (tile - 16) * 4 + (n >> 2);   // dec V row
            af[i][0] = ld8h(dwih + r * 64 + q * 8);
            af[i][1] = ld8h(dwih + r * 64 + 32 + q * 8);
            af[i][2] = ld8h(dwhh + r * 32 + q * 8);
        }
    }

    // ---- biases (phase-2 threads, fp32) + recurrent cell state ----
    float b0 = 0.f, b1 = 0.f, b2 = 0.f, b3 = 0.f, c_st = 0.f;
    if (t < 64) {
        b0 = ebih[t]       + ebhh[t];
        b1 = ebih[64 + t]  + ebhh[64 + t];
        b2 = ebih[128 + t] + ebhh[128 + t];
        b3 = ebih[192 + t] + ebhh[192 + t];
    } else if (t < 96) {
        int u = t - 64;
        b0 = dbih[u]      + dbhh[u];
        b1 = dbih[32 + u] + dbhh[32 + u];
        b2 = dbih[64 + u] + dbhh[64 + u];
        b3 = dbih[96 + u] + dbhh[96 + u];
    }

    // ---- prologue: zero Bst, stage x chunk 0 (fp32), stage x[0] into B col 0 ----
    { u32* bz = (u32*)&Bst[0][0]; for (int i2 = t; i2 < 16 * 104 / 2; i2 += 256) bz[i2] = 0u; }
    const float* xb = x + (size_t)b * TT * FF;
    *(float4*)&xst[0][t * 8]     = *(const float4*)(xb + t * 8);
    *(float4*)&xst[0][t * 8 + 4] = *(const float4*)(xb + t * 8 + 4);
    __syncthreads();
    if (t >= 96 && t < 128) Bst[0][64 + (t - 96)] = (f16)xst[0][t - 96];
    __syncthreads();

    for (int tt = 0; tt <= TT; ++tt) {
        // x chunk prefetch (writes the buffer not being read this 64-step window)
        if ((tt & 63) == 0) {
            int cn = (tt >> 6) + 1;
            if (cn < 16) {
                *(float4*)&xst[cn & 1][t * 8]     = *(const float4*)(xb + cn * 2048 + t * 8);
                *(float4*)&xst[cn & 1][t * 8 + 4] = *(const float4*)(xb + cn * 2048 + t * 8 + 4);
            }
        }

        // ---- phase 1: B fragments + 18 MFMAs/wave ----
        half8 bf0 = *(const half8*)&Bst[n][q * 8];
        half8 bf1 = *(const half8*)&Bst[n][32 + q * 8];
        half8 bf2 = *(const half8*)&Bst[n][64 + q * 8];

        v4f zero = {0.f, 0.f, 0.f, 0.f};
        v4f acc[6];
#pragma unroll
        for (int i = 0; i < 6; ++i)
            acc[i] = __builtin_amdgcn_mfma_f32_16x16x32_f16(af[i][0], bf0, zero, 0, 0, 0);
#pragma unroll
        for (int i = 0; i < 6; ++i)
            acc[i] = __builtin_amdgcn_mfma_f32_16x16x32_f16(af[i][1], bf1, acc[i], 0, 0, 0);
#pragma unroll
        for (int i = 0; i < 6; ++i)
            acc[i] = __builtin_amdgcn_mfma_f32_16x16x32_f16(af[i][2], bf2, acc[i], 0, 0, 0);

        // hi/lo partials to LDS (predicated ds_write_b128, 8 active lanes per tile)
#pragma unroll
        for (int i = 0; i < 6; ++i) {
            int tile = w * 6 + i;
            if (tile < 16) {
                if (n < 2) *(v4f*)&gpart[n][(tile * 4 + q) * 4] = acc[i];
            } else {
                if (n == 2 || n == 3)
                    *(v4f*)&gpart[n - 2][(64 + (tile - 16) * 4 + q) * 4] = acc[i];
            }
        }
        __syncthreads();

        // ---- phase 2: nonlinear unit updates + B write-back ----
        if (t < 64) {                     // encoder unit t, step tt
            if (tt < TT) {
                v4f gh = *(const v4f*)&gpart[0][t * 4];
                v4f gl = *(const v4f*)&gpart[1][t * 4];
                float i_ = sigm(gh[0] + gl[0] + b0);
                float f_ = sigm(gh[1] + gl[1] + b1);
                float g_ = tanhf(gh[2] + gl[2] + b2);
                float o_ = sigm(gh[3] + gl[3] + b3);
                c_st = f_ * c_st + i_ * g_;
                float h = o_ * tanhf(c_st);
                f16 hi = (f16)h;
                f16 lo = (f16)(h - (float)hi);
                Bst[0][t] = hi; Bst[2][t] = hi;
                Bst[1][t] = lo; Bst[3][t] = lo;
            }
        } else if (t < 96) {              // decoder unit t-64, step tt-1
            if (tt >= 1) {
                int u = t - 64;
                v4f gh = *(const v4f*)&gpart[0][(64 + u) * 4];
                v4f gl = *(const v4f*)&gpart[1][(64 + u) * 4];
                float i_ = sigm(gh[0] + gl[0] + b0);
                float f_ = sigm(gh[1] + gl[1] + b1);
                float g_ = tanhf(gh[2] + gl[2] + b2);
                float o_ = sigm(gh[3] + gl[3] + b3);
                c_st = f_ * c_st + i_ * g_;
                float h = o_ * tanhf(c_st);
                f16 hi = (f16)h;
                f16 lo = (f16)(h - (float)hi);
                Bst[2][64 + u] = hi;
                Bst[3][64 + u] = lo;
                out[(size_t)b * TT * FF + (size_t)(tt - 1) * FF + u] = h;
            }
        } else if (t < 128) {             // stage x for enc step tt+1 into B col 0
            int st = tt + 1;
            if (st < TT) {
                int j = t - 96;
                Bst[0][64 + j] = (f16)xst[(st >> 6) & 1][(st & 63) * 32 + j];
            }
        }
        __syncthreads();
    }
}

extern "C" void kernel_launch(void* const* d_in, const int* in_sizes, int n_in,
                              void* d_out, int out_size, void* d_ws, size_t ws_size,
                              hipStream_t stream) {
    (void)in_sizes; (void)n_in; (void)out_size; (void)d_ws; (void)ws_size;
    lstm_ae_mfma<<<512, 256, 0, stream>>>((const float*)d_in[0],
                                          (const float*)d_in[1], (const float*)d_in[2],
                                          (const float*)d_in[3], (const float*)d_in[4],
                                          (const float*)d_in[5], (const float*)d_in[6],
                                          (const float*)d_in[7], (const float*)d_in[8],
                                          (float*)d_out);
}